// Round 5
// baseline (62.259 us; speedup 1.0000x reference)
//
#include <hip/hip_runtime.h>

// BoxRenderLoss, closed-form + single fused launch.
// Closed form: the 100 boundary samples = 4 axis-aligned edges x 25 evenly
// spaced points; min over samples = min over edges of perp^2 + (along-residual
// to nearest sample)^2, nearest index = clamp(rint(24*r/w), 0, 24).
// Reduction: each block publishes its f32 partial inside a tagged 64-bit
// device-scope atomic slot; block 0 polls all slots and writes the scalar.
// (ws is harness-poisoned to 0xAA each launch, so hi-word 0xAAAAAAAA != MAGIC.)

constexpr int FP = 100;           // 10x10 fragment grid
constexpr int QUADS_PER_BOX = 50; // 200 items (2 dirs x 100 frags) / 4 per thread
constexpr unsigned MAGIC = 0x5E0D1F2Bu;

__global__ __launch_bounds__(256) void box_loss_fused(
    const float4* __restrict__ boxes, const float4* __restrict__ targets,
    unsigned long long* __restrict__ slots, int B, int nblocks, float scale,
    float* __restrict__ out)
{
    const int gtid = blockIdx.x * 256 + threadIdx.x;   // quad index
    const int t = threadIdx.x;
    float acc = 0.0f;

    if (gtid < B * QUADS_PER_BOX) {
        const int b  = gtid / QUADS_PER_BOX;
        const int q  = gtid - b * QUADS_PER_BOX;
        const int j0 = q * 4;                 // item in [0,200): 4 consecutive, same direction
        const int d  = (j0 >= FP);            // 0: box-frag vs target; 1: target-frag vs box

        const float4 bx = boxes[b];
        const float4 tg = targets[b];
        const float4 s = d ? tg : bx;         // fragment source box
        const float4 o = d ? bx : tg;         // other box (outside test + boundary)

        const float swx = s.z - s.x, swy = s.w - s.y;
        const float owx = o.z - o.x, owy = o.w - o.y;
        const float iwx = 24.0f / owx,          iwy = 24.0f / owy;   // inf/nan ok (clamped)
        const float wx24 = owx * (1.0f/24.0f),  wy24 = owy * (1.0f/24.0f);

        const int f0 = j0 - d * FP;           // fragment index base
        #pragma unroll
        for (int k = 0; k < 4; ++k) {
            const int f = f0 + k;
            const float fu = (float)(f / 10) * (1.0f/9.0f);
            const float fv = (float)(f % 10) * (1.0f/9.0f);
            const float px = fmaf(fu, swx, s.x);
            const float py = fmaf(fv, swy, s.y);
            const float rx = px - o.x, ry = py - o.y;

            // outside = NOT(rx>=0 && ry>=0 && o.z-px>=0 && o.w-py>=0)
            const bool outside = (rx < 0.0f) || (ry < 0.0f) || (px > o.z) || (py > o.w);
            if (outside) {
                float tx = rintf(rx * iwx); tx = fminf(fmaxf(tx, 0.0f), 24.0f);
                float ty = rintf(ry * iwy); ty = fminf(fmaxf(ty, 0.0f), 24.0f);
                const float dax = fmaf(-tx, wx24, rx);   // along-x residual to nearest sample
                const float day = fmaf(-ty, wy24, ry);   // along-y residual
                const float ax = dax * dax, ay = day * day;
                const float ex0 = rx * rx;
                const float ex1 = (rx - owx) * (rx - owx);
                const float ey0 = ry * ry;
                const float ey1 = (ry - owy) * (ry - owy);
                // 4 edges: x=lo, x=hi (share ay); y=lo, y=hi (share ax)
                acc += fminf(fminf(ex0 + ay, ex1 + ay), fminf(ax + ey0, ax + ey1));
            }
        }
    }

    // block reduction: wave64 shuffle + 4-way LDS
    for (int off = 32; off > 0; off >>= 1) acc += __shfl_down(acc, off, 64);
    __shared__ float wsum[4];
    if ((t & 63) == 0) wsum[t >> 6] = acc;
    __syncthreads();
    if (t == 0) {
        const float part = wsum[0] + wsum[1] + wsum[2] + wsum[3];
        const unsigned long long v =
            ((unsigned long long)MAGIC << 32) | (unsigned long long)__float_as_uint(part);
        __hip_atomic_store(&slots[blockIdx.x], v, __ATOMIC_RELEASE, __HIP_MEMORY_SCOPE_AGENT);
    }

    if (blockIdx.x != 0) return;

    // block 0: poll every block's slot (value rides inside the atomic), sum, write out
    float s = 0.0f;
    for (int i = t; i < nblocks; i += 256) {
        unsigned long long v;
        while (((v = __hip_atomic_load(&slots[i], __ATOMIC_ACQUIRE,
                                       __HIP_MEMORY_SCOPE_AGENT)) >> 32) != MAGIC) {
            __builtin_amdgcn_s_sleep(1);
        }
        s += __uint_as_float((unsigned)v);
    }
    for (int off = 32; off > 0; off >>= 1) s += __shfl_down(s, off, 64);
    __syncthreads();                       // wsum reuse
    if ((t & 63) == 0) wsum[t >> 6] = s;
    __syncthreads();
    if (t == 0) out[0] = (wsum[0] + wsum[1] + wsum[2] + wsum[3]) * scale;
}

extern "C" void kernel_launch(void* const* d_in, const int* in_sizes, int n_in,
                              void* d_out, int out_size, void* d_ws, size_t ws_size,
                              hipStream_t stream) {
    const float4* boxes   = (const float4*)d_in[0];
    const float4* targets = (const float4*)d_in[1];
    const int B = in_sizes[0] / 4;

    const int nthreads = B * QUADS_PER_BOX;        // 204800 for B=4096
    const int nblocks  = (nthreads + 255) / 256;   // 800

    const float scale = 1.0f / (2.0f * (float)B * (float)FP);
    box_loss_fused<<<nblocks, 256, 0, stream>>>(
        boxes, targets, (unsigned long long*)d_ws, B, nblocks, scale, (float*)d_out);
}